// Round 7
// baseline (578.927 us; speedup 1.0000x reference)
//
#include <hip/hip_runtime.h>
#include <hip/hip_bf16.h>

#define TT 512
#define DD 512
#define VV 2048
#define HH 128

typedef __attribute__((ext_vector_type(8))) short bf16x8;
typedef __attribute__((ext_vector_type(8))) unsigned short ushort8;
typedef __attribute__((ext_vector_type(4))) unsigned short ushort4v;
typedef __attribute__((ext_vector_type(4))) float f32x4;

__device__ __forceinline__ unsigned short f2bf(float f) {
  union { __hip_bfloat16 b; unsigned short u; } cv;
  cv.b = __float2bfloat16(f);
  return cv.u;
}

// LDS-only barrier: orders ds ops across waves without draining vmcnt,
// so global prefetches stay in flight across the barrier.
__device__ __forceinline__ void lds_barrier() {
  asm volatile("s_waitcnt lgkmcnt(0)\n\ts_barrier" ::: "memory");
}

__global__ void cvt_x_kernel(const float* __restrict__ x, unsigned short* __restrict__ xb) {
  const int i = blockIdx.x * blockDim.x + threadIdx.x;
  const float4 f = ((const float4*)x)[i];
  ushort4v u;
  u[0] = f2bf(f.x); u[1] = f2bf(f.y); u[2] = f2bf(f.z); u[3] = f2bf(f.w);
  ((ushort4v*)xb)[i] = u;
}

// One WG per voxel; 512 thr = 8 waves; wave w owns t-rows [w*64, +64).
// Weight staging = HIGH-HALF ushort loads (bf16 by truncation): 4x fewer
// return bytes than float2 fp32, CVT becomes a register pack. A uniform
// stream of 10 tiles (t=0..7: W1 k-tiles of 64 rows; t=8,9: W2 halves)
// flows through a ring-3 register pipeline; strict oldest-first waits keep
// >=1 full tile of loads in flight at every stall point.
// Per wave per tile: rows w*8+jr (jr<8); lane l holds cols {l, 64+l}.
// LDS map (64 KiB):
//   [0, 32768)      : W2[v] bf16, frag-linear, k-chunk ki at ki*8 KiB
//   [32768, 65536)  : W1 ring 2 x 16 KiB (phase A) / h1 8 x 4 KiB (phase B)
__global__ __launch_bounds__(512, 2)
void voxel_mlp_kernel(const unsigned short* __restrict__ Xb,
                      const float* __restrict__ W1,
                      const float* __restrict__ b1,
                      const float* __restrict__ W2,
                      const float* __restrict__ b2,
                      const float* __restrict__ W3,
                      const float* __restrict__ b3,
                      float* __restrict__ out) {
  __shared__ __align__(16) char LDS[65536];
  constexpr unsigned W2BASE = 0;
  constexpr unsigned R1     = 32768;
  constexpr unsigned H1BASE = 32768;

  const int v   = blockIdx.x;
  const int tid = threadIdx.x;
  const int w   = tid >> 6;
  const int l   = tid & 63;
  const int lg  = l >> 4;
  const int ll  = l & 15;

  const unsigned short* W1us = (const unsigned short*)(W1 + (size_t)v * DD * HH);
  const unsigned short* W2us = (const unsigned short*)(W2 + (size_t)v * HH * HH);

  unsigned stg[3][16];   // ring-3 staging: 8 rows x 2 col-halves, zext ushorts

#define ISSUE_STG(t)                                                        \
  { const unsigned short* gp =                                              \
      ((t) < 8 ? W1us + (t) * 64 * 2 * HH : W2us + ((t) - 8) * 64 * 2 * HH) \
      + (w * 8) * 2 * HH + 1;                                               \
    _Pragma("unroll") for (int jr = 0; jr < 8; ++jr) {                      \
      stg[(t) % 3][jr]     = gp[jr * 2 * HH + 2 * l];                       \
      stg[(t) % 3][8 + jr] = gp[jr * 2 * HH + 2 * (64 + l)]; } }

#define CVT_STG(t)                                                          \
  { ushort8 e0, e1;                                                         \
    _Pragma("unroll") for (int jr = 0; jr < 8; ++jr) {                      \
      e0[jr] = (unsigned short)stg[(t) % 3][jr];                            \
      e1[jr] = (unsigned short)stg[(t) % 3][8 + jr]; }                      \
    const unsigned base_ =                                                  \
      ((t) < 8 ? R1 + (unsigned)((t) & 1) * 16384u                          \
               : W2BASE + (unsigned)((t) - 8) * 16384u)                     \
      + (unsigned)(w >> 2) * 8192u;                                         \
    const unsigned wb = (unsigned)((w & 3) * 256 + (l & 15) * 16);          \
    const unsigned n0 = (unsigned)(l >> 4), n1 = n0 + 4u;                   \
    *(ushort8*)(&LDS[base_ + n0 * 1024u + (wb ^ (n0 << 4))]) = e0;          \
    *(ushort8*)(&LDS[base_ + n1 * 1024u + (wb ^ (n1 << 4))]) = e1; }

  // ---- prologue: tiles 0..2 issued; tile 0 to LDS slot 0 ----
  ISSUE_STG(0);
  ISSUE_STG(1);
  ISSUE_STG(2);
  CVT_STG(0);          // waits tile 0 (oldest); tiles 1,2 stay in flight
  lds_barrier();

  f32x4 acc1[4][8];
#pragma unroll
  for (int mi = 0; mi < 4; ++mi)
#pragma unroll
    for (int n = 0; n < 8; ++n) acc1[mi][n] = f32x4{0.f, 0.f, 0.f, 0.f};

  // ---- phase A: layer 1, K over D in 8 steps of 64 ----
#pragma unroll
  for (int s = 0; s < 8; ++s) {
    // A-frags FIRST (oldest vm ops of the step): MFMA's wait on them never
    // drains the younger stage-tile prefetches.
    bf16x8 aS[2][4];
#pragma unroll
    for (int u = 0; u < 2; ++u)
#pragma unroll
      for (int mi = 0; mi < 4; ++mi)
        aS[u][mi] = *(const bf16x8*)(Xb + (size_t)(w * 64 + mi * 16 + ll) * DD +
                                     s * 64 + u * 32 + lg * 8);

    if (s + 3 <= 9) ISSUE_STG(s + 3);

    // convert tile s+1 (issued 3 steps ago; counted wait leaves newer in flight)
    CVT_STG(s + 1);

    // 64 MFMAs on ring slot s&1
#pragma unroll
    for (int u = 0; u < 2; ++u)
#pragma unroll
      for (int n = 0; n < 8; ++n) {
        const bf16x8 b = *(const bf16x8*)(&LDS[R1 + (unsigned)(s & 1) * 16384u +
                                               (unsigned)u * 8192u + (unsigned)n * 1024u +
                                               (((unsigned)l * 16u) ^ ((unsigned)(n & 7) << 4))]);
#pragma unroll
        for (int mi = 0; mi < 4; ++mi)
          acc1[mi][n] = __builtin_amdgcn_mfma_f32_16x16x32_bf16(aS[u][mi], b, acc1[mi][n], 0, 0, 0);
      }

    lds_barrier();
  }

  CVT_STG(9);          // W2 second half (issued at step 6)
  lds_barrier();

#undef ISSUE_STG
#undef CVT_STG

  // biases / head weights (fp32, exact)
  float b1v[8], b2v[8], w3v[8];
#pragma unroll
  for (int n = 0; n < 8; ++n) {
    b1v[n] = b1[v * HH + n * 16 + ll];
    b2v[n] = b2[v * HH + n * 16 + ll];
    w3v[n] = W3[v * HH + n * 16 + ll];
  }
  const float b3v = b3[v];

  const unsigned slot = H1BASE + (unsigned)w * 4096u;  // wave-private 16x128 bf16

  // ---- phase B: layers 2+3, per 16-row block (wave-private, no barriers) ----
#pragma unroll
  for (int mi = 0; mi < 4; ++mi) {
#pragma unroll
    for (int n = 0; n < 8; ++n) {
#pragma unroll
      for (int r = 0; r < 4; ++r) {
        const int tl = lg * 4 + r;
        float hv = acc1[mi][n][r] + b1v[n];
        hv = fmaxf(hv, 0.f);
        const int h = n * 16 + ll;
        const unsigned byte = slot + (unsigned)tl * 256u +
                              (unsigned)((h * 2) ^ ((tl & 7) << 4));
        *(unsigned short*)(&LDS[byte]) = f2bf(hv);
      }
    }
    f32x4 acc2[8];
#pragma unroll
    for (int m = 0; m < 8; ++m) acc2[m] = f32x4{0.f, 0.f, 0.f, 0.f};
#pragma unroll
    for (int ki = 0; ki < 4; ++ki) {
      const int k0 = ki * 32 + lg * 8;
      const unsigned abyte = slot + (unsigned)ll * 256u +
                             (unsigned)((k0 * 2) ^ ((ll & 7) << 4));
      const bf16x8 a2 = *(const bf16x8*)(&LDS[abyte]);
#pragma unroll
      for (int m = 0; m < 8; ++m) {
        const bf16x8 bw = *(const bf16x8*)(&LDS[W2BASE + (unsigned)ki * 8192u +
                                                (unsigned)m * 1024u +
                                                (((unsigned)l * 16u) ^ ((unsigned)(m & 7) << 4))]);
        acc2[m] = __builtin_amdgcn_mfma_f32_16x16x32_bf16(a2, bw, acc2[m], 0, 0, 0);
      }
    }
#pragma unroll
    for (int r = 0; r < 4; ++r) {
      float p = 0.f;
#pragma unroll
      for (int m = 0; m < 8; ++m)
        p += fmaxf(acc2[m][r] + b2v[m], 0.f) * w3v[m];
      p += __shfl_xor(p, 1);
      p += __shfl_xor(p, 2);
      p += __shfl_xor(p, 4);
      p += __shfl_xor(p, 8);
      if (ll == 0) {
        const int t = w * 64 + mi * 16 + lg * 4 + r;
        out[t * VV + v] = p + b3v;
      }
    }
  }
}

extern "C" void kernel_launch(void* const* d_in, const int* in_sizes, int n_in,
                              void* d_out, int out_size, void* d_ws, size_t ws_size,
                              hipStream_t stream) {
  const float* X  = (const float*)d_in[0];
  const float* W1 = (const float*)d_in[1];
  const float* b1 = (const float*)d_in[2];
  const float* W2 = (const float*)d_in[3];
  const float* b2 = (const float*)d_in[4];
  const float* W3 = (const float*)d_in[5];
  const float* b3 = (const float*)d_in[6];
  float* out = (float*)d_out;

  unsigned short* Xb = (unsigned short*)d_ws;   // 512 KiB bf16 X

  cvt_x_kernel<<<256, 256, 0, stream>>>(X, Xb);
  voxel_mlp_kernel<<<VV, 512, 0, stream>>>(Xb, W1, b1, W2, b2, W3, b3, out);
}

// Round 9
// 532.891 us; speedup vs baseline: 1.0864x; 1.0864x over previous
//
#include <hip/hip_runtime.h>
#include <hip/hip_bf16.h>

#define TT 512
#define DD 512
#define VV 2048
#define HH 128

typedef __attribute__((ext_vector_type(8))) short bf16x8;
typedef __attribute__((ext_vector_type(8))) unsigned short ushort8;
typedef __attribute__((ext_vector_type(4))) unsigned short ushort4v;
typedef __attribute__((ext_vector_type(16))) float f32x16;

__device__ __forceinline__ unsigned short f2bf(float f) {
  union { __hip_bfloat16 b; unsigned short u; } cv;
  cv.b = __float2bfloat16(f);
  return cv.u;
}

// LDS-only barrier: does NOT drain vmcnt (global streams stay in flight).
__device__ __forceinline__ void lds_barrier() {
  asm volatile("s_waitcnt lgkmcnt(0)\n\ts_barrier" ::: "memory");
}

// Pre-pass: X fp32 -> bf16 once (shared by all voxels, L2-resident).
__global__ void cvt_x_kernel(const float* __restrict__ x, unsigned short* __restrict__ xb) {
  const int i = blockIdx.x * blockDim.x + threadIdx.x;
  const float4 f = ((const float4*)x)[i];
  ushort4v u;
  u[0] = f2bf(f.x); u[1] = f2bf(f.y); u[2] = f2bf(f.z); u[3] = f2bf(f.w);
  ((ushort4v*)xb)[i] = u;
}

// One WG = one voxel. Phase A (layer 1) is BARRIER-FREE: 8 waves = 4 row-bands
// (rb: 128 t-rows) x 2 col-halves (cs: 64 h-cols); each wave's W1 columns are
// private, streamed global->regs (ring-3, consume-then-reissue)->bf16 pack->
// MFMA B-operand. 32x32x16 MFMA; acc1[4][2] f32x16 = 128 VGPR.
// Phase B: W2 staged ONCE to LDS (frag-linear); 2 halves of 256 t-rows; wave
// owns 32 rows x all 128 cols -> layer-3 reduced in-wave, plain stores.
// LDS: [0,32K) W2L frag-linear; [32K,96K) h1 half [256 rows][256 B] swizzled.
__global__ __launch_bounds__(512, 2)
void voxel_mlp_kernel(const unsigned short* __restrict__ Xb,
                      const float* __restrict__ W1,
                      const float* __restrict__ b1,
                      const float* __restrict__ W2,
                      const float* __restrict__ b2,
                      const float* __restrict__ W3,
                      const float* __restrict__ b3,
                      float* __restrict__ out) {
  __shared__ __align__(16) char LDS[98304];
  constexpr unsigned W2BASE = 0;
  constexpr unsigned H1BASE = 32768;

  const int v   = blockIdx.x;
  const int tid = threadIdx.x;
  const int w   = tid >> 6;
  const int l   = tid & 63;
  const int l31 = l & 31;
  const int hi  = l >> 5;
  const int rb  = w >> 1;    // row-band 0..3 (128 t-rows each)
  const int cs  = w & 1;     // col-half 0..1 (64 h-cols each)

  const float* W1c = W1 + (size_t)v * DD * HH + cs * 64 + l31;
  const unsigned short* XA = Xb + (size_t)(rb * 128 + l31) * DD + hi * 8;

  float  w1s[3][2][8];   // ring-3 W1 staging (48 regs), statically indexed
  bf16x8 aS[2][4];       // A-frag double buffer

#define ISSUE_B(t)                                                       \
  { const float* gp = W1c + ((t) * 16 + hi * 8) * HH;                    \
    _Pragma("unroll") for (int n = 0; n < 2; ++n)                        \
      _Pragma("unroll") for (int j = 0; j < 8; ++j)                      \
        w1s[(t) % 3][n][j] = gp[j * HH + n * 32]; }

#define ISSUE_A(s)                                                       \
  { _Pragma("unroll") for (int lt = 0; lt < 4; ++lt)                     \
      aS[(s) & 1][lt] = *(const bf16x8*)(XA + lt * 32 * DD + (s) * 16); }

  ISSUE_B(0);
  ISSUE_B(1);
  ISSUE_B(2);
  ISSUE_A(0);

  f32x16 acc1[4][2];
#pragma unroll
  for (int lt = 0; lt < 4; ++lt)
#pragma unroll
    for (int n = 0; n < 2; ++n)
#pragma unroll
      for (int r = 0; r < 16; ++r) acc1[lt][n][r] = 0.f;

  // ---- phase A: layer 1, K=512 in 32 steps of 16, zero barriers ----
#pragma unroll
  for (int s = 0; s < 32; ++s) {
    // pack FIRST (reads ring slot s%3 before it is re-issued below)
    bf16x8 bF[2];
#pragma unroll
    for (int n = 0; n < 2; ++n)
#pragma unroll
      for (int j = 0; j < 8; ++j)
        bF[n][j] = (short)f2bf(w1s[s % 3][n][j]);

    if (s < 31) ISSUE_A(s + 1);
    if (s < 29) ISSUE_B(s + 3);   // slot s%3 is free now (consumed above)

#pragma unroll
    for (int lt = 0; lt < 4; ++lt)
#pragma unroll
      for (int n = 0; n < 2; ++n)
        acc1[lt][n] = __builtin_amdgcn_mfma_f32_32x32x16_bf16(aS[s & 1][lt], bF[n], acc1[lt][n], 0, 0, 0);
  }
#undef ISSUE_B
#undef ISSUE_A

  // biases / head weights (fp32, exact) — issued before W2 stage loads so
  // waiting on them never drains the W2 stream
  float b1v[2];
#pragma unroll
  for (int n = 0; n < 2; ++n) b1v[n] = b1[v * HH + cs * 64 + n * 32 + l31];
  float b2v[4], w3v[4];
#pragma unroll
  for (int n = 0; n < 4; ++n) {
    b2v[n] = b2[v * HH + n * 32 + l31];
    w3v[n] = W3[v * HH + n * 32 + l31];
  }
  const float b3v = b3[v];

  // W2 -> LDS stage loads (one time): wave w stages k-rows [w*16, +16)
  float w2s[4][8];
  {
    const float* gp = W2 + (size_t)v * HH * HH + (w * 16 + hi * 8) * HH + l31;
#pragma unroll
    for (int cb = 0; cb < 4; ++cb)
#pragma unroll
      for (int j = 0; j < 8; ++j)
        w2s[cb][j] = gp[j * HH + cb * 32];
  }

  // ---- phase B: 2 halves of 256 t-rows ----
#pragma unroll
  for (int H = 0; H < 2; ++H) {
    // h1 writes for this half (4 waves with rb>>1 == H), swizzled 2-B scatter
    if ((rb >> 1) == H) {
      const int rbase = (rb & 1) * 128;
#pragma unroll
      for (int lt = 0; lt < 4; ++lt)
#pragma unroll
        for (int n = 0; n < 2; ++n) {
          const int hcol = cs * 64 + n * 32 + l31;
#pragma unroll
          for (int r = 0; r < 16; ++r) {
            const int rowh = rbase + lt * 32 + (r & 3) + 8 * (r >> 2) + 4 * hi;
            const float hv = fmaxf(acc1[lt][n][r] + b1v[n], 0.f);
            const unsigned byte = H1BASE + (unsigned)rowh * 256u +
                                  (unsigned)((hcol * 2) ^ ((rowh & 15) << 4));
            *(unsigned short*)(&LDS[byte]) = f2bf(hv);
          }
        }
    }
    if (H == 0) {
      // pack + write W2L (frag-linear: chunk [ks=w][cb][lane] = 16 B)
#pragma unroll
      for (int cb = 0; cb < 4; ++cb) {
        ushort8 e;
#pragma unroll
        for (int j = 0; j < 8; ++j) e[j] = f2bf(w2s[cb][j]);
        *(ushort8*)(&LDS[W2BASE + (unsigned)w * 4096u + (unsigned)cb * 1024u +
                         (unsigned)l * 16u]) = e;
      }
    }
    lds_barrier();

    // layer 2: wave w owns rows [w*32, +32) of this half, all 128 cols
    f32x16 acc2[4];
#pragma unroll
    for (int n = 0; n < 4; ++n)
#pragma unroll
      for (int r = 0; r < 16; ++r) acc2[n][r] = 0.f;

    const int rowA = w * 32 + l31;
#pragma unroll
    for (int ks = 0; ks < 8; ++ks) {
      const unsigned abyte = H1BASE + (unsigned)rowA * 256u +
                             (unsigned)(((ks * 16 + hi * 8) * 2) ^ ((rowA & 15) << 4));
      const bf16x8 a2 = *(const bf16x8*)(&LDS[abyte]);
#pragma unroll
      for (int n = 0; n < 4; ++n) {
        const bf16x8 bw = *(const bf16x8*)(&LDS[W2BASE + (unsigned)ks * 4096u +
                                                (unsigned)n * 1024u + (unsigned)l * 16u]);
        acc2[n] = __builtin_amdgcn_mfma_f32_32x32x16_bf16(a2, bw, acc2[n], 0, 0, 0);
      }
    }
    lds_barrier();   // h1 reads done; next half may overwrite

    // layer 3: relu(acc2+b2).w3 over 128 cols, fully in-wave, plain store
#pragma unroll
    for (int r = 0; r < 16; ++r) {
      float p = 0.f;
#pragma unroll
      for (int n = 0; n < 4; ++n)
        p += fmaxf(acc2[n][r] + b2v[n], 0.f) * w3v[n];
      p += __shfl_xor(p, 1);
      p += __shfl_xor(p, 2);
      p += __shfl_xor(p, 4);
      p += __shfl_xor(p, 8);
      p += __shfl_xor(p, 16);
      if (l31 == 0) {
        const int t = H * 256 + w * 32 + (r & 3) + 8 * (r >> 2) + 4 * hi;
        out[t * VV + v] = p + b3v;
      }
    }
  }
}

extern "C" void kernel_launch(void* const* d_in, const int* in_sizes, int n_in,
                              void* d_out, int out_size, void* d_ws, size_t ws_size,
                              hipStream_t stream) {
  const float* X  = (const float*)d_in[0];
  const float* W1 = (const float*)d_in[1];
  const float* b1 = (const float*)d_in[2];
  const float* W2 = (const float*)d_in[3];
  const float* b2 = (const float*)d_in[4];
  const float* W3 = (const float*)d_in[5];
  const float* b3 = (const float*)d_in[6];
  float* out = (float*)d_out;

  unsigned short* Xb = (unsigned short*)d_ws;   // 512 KiB bf16 X

  cvt_x_kernel<<<256, 256, 0, stream>>>(X, Xb);
  voxel_mlp_kernel<<<VV, 512, 0, stream>>>(Xb, W1, b1, W2, b2, W3, b3, out);
}

// Round 10
// 298.105 us; speedup vs baseline: 1.9420x; 1.7876x over previous
//
#include <hip/hip_runtime.h>
#include <hip/hip_bf16.h>

#define TT 512
#define DD 512
#define VV 2048
#define HH 128

typedef __attribute__((ext_vector_type(8))) short bf16x8;
typedef __attribute__((ext_vector_type(8))) unsigned short ushort8;
typedef __attribute__((ext_vector_type(4))) unsigned short ushort4v;
typedef __attribute__((ext_vector_type(4))) float f32x4;

__device__ __forceinline__ unsigned short f2bf(float f) {
  union { __hip_bfloat16 b; unsigned short u; } cv;
  cv.b = __float2bfloat16(f);
  return cv.u;
}

// LDS-only barrier: orders ds ops across waves without draining vmcnt,
// so global_load_lds prefetches stay in flight across the barrier.
__device__ __forceinline__ void lds_barrier() {
  asm volatile("s_waitcnt lgkmcnt(0)\n\ts_barrier" ::: "memory");
}

// Counted vmem gate: wait until <= N vmem ops outstanding (keeps the
// youngest N -- the next-tile global_load_lds stream -- in flight).
#define VM_GATE(N)                                                   \
  do {                                                               \
    asm volatile("s_waitcnt vmcnt(" #N ")" ::: "memory");            \
    __builtin_amdgcn_sched_barrier(0);                               \
  } while (0)

__global__ void cvt_x_kernel(const float* __restrict__ x, unsigned short* __restrict__ xb) {
  const int i = blockIdx.x * blockDim.x + threadIdx.x;
  const float4 f = ((const float4*)x)[i];
  ushort4v u;
  u[0] = f2bf(f.x); u[1] = f2bf(f.y); u[2] = f2bf(f.z); u[3] = f2bf(f.w);
  ((ushort4v*)xb)[i] = u;
}

// One WG = one voxel; 512 thr = 8 waves; wave w owns t-rows [w*64,+64).
// Phase A: K-step 64. W1 fp32 tile [64k][128h] streamed HBM->LDS via
// global_load_lds dwordx4 (no VGPR staging -> compiler cannot sink the
// prefetch; depth held by counted vmcnt gates, never drained to 0).
// Each step: gate(vmcnt 4) -> barrier -> in-LDS fp32->bf16 convert into a
// frag-linear tile (thread (w,l) owns frag col-block n=w) -> barrier ->
// ds_read_b128 frags + 64x mfma_16x16x32_bf16.
// LDS map (96 KiB):
//   [0, 65536)      : W1 fp32 tile double buffer (2 x 32 KiB)   (phase A)
//   [65536, 81920)  : bf16 frag tile F [2 ksub][8 n][64 lane]   (phase A)
//   [0, 32768)      : W2 bf16 frag-linear [4 ki][8 m][64 lane]  (phase B)
//   [32768, 65536)  : h1 per-wave slots 8 x 4 KiB, XOR-swizzled (phase B)
__global__ __launch_bounds__(512, 2)
void voxel_mlp_kernel(const unsigned short* __restrict__ Xb,
                      const float* __restrict__ W1,
                      const float* __restrict__ b1,
                      const float* __restrict__ W2,
                      const float* __restrict__ b2,
                      const float* __restrict__ W3,
                      const float* __restrict__ b3,
                      float* __restrict__ out) {
  __shared__ __align__(16) char LDS[98304];
  constexpr unsigned GBASE  = 0;       // fp32 W1 tile dbuf
  constexpr unsigned FBASE  = 65536;   // bf16 frag tile
  constexpr unsigned W2BASE = 0;       // phase B (aliases dead G)
  constexpr unsigned H1BASE = 32768;   // phase B (aliases dead G)

  const int v   = blockIdx.x;
  const int tid = threadIdx.x;
  const int w   = tid >> 6;
  const int l   = tid & 63;
  const int lg  = l >> 4;
  const int ll  = l & 15;

  const float* W1v = W1 + (size_t)v * DD * HH;
  const float* W2v = W2 + (size_t)v * HH * HH;

  // global_load_lds: wave w, instr p covers rows w*8 + p*2 + (l>>5),
  // cols (l&31)*4 .. +4 of the 64x128 tile (16 B/lane, fully coalesced).
  const size_t gsrc_lane = (size_t)((w * 8 + (l >> 5)) * HH + (l & 31) * 4);

#define G_ISSUE(t)                                                         \
  { const float* gp = W1v + (size_t)(t) * 64 * HH + gsrc_lane;             \
    const unsigned ldst = GBASE + (unsigned)((t) & 1) * 32768u +           \
                          (unsigned)w * 4096u;                             \
    _Pragma("unroll") for (int p = 0; p < 4; ++p)                          \
      __builtin_amdgcn_global_load_lds(                                    \
        (const __attribute__((address_space(1))) void*)(gp + p * 2 * HH),  \
        (__attribute__((address_space(3))) void*)(&LDS[ldst + p * 1024u]), \
        16, 0, 0); }

  // ---- prologue: tiles 0,1 in flight ----
  G_ISSUE(0);
  G_ISSUE(1);

  f32x4 acc1[4][8];
#pragma unroll
  for (int mi = 0; mi < 4; ++mi)
#pragma unroll
    for (int n = 0; n < 8; ++n) acc1[mi][n] = f32x4{0.f, 0.f, 0.f, 0.f};

  // ---- phase A: layer 1, K=512 in 8 steps of 64 ----
#pragma unroll
  for (int s = 0; s < 8; ++s) {
    VM_GATE(4);        // tile s landed; tile s+1 (4 ops) stays in flight
    lds_barrier();     // all waves' tile-s writes visible

    // A-frags (L2-resident bf16 X): 8 x b128, issued before G(s+2) so the
    // compiler's counted wait on them never drains the G stream
    bf16x8 aF[2][4];
#pragma unroll
    for (int ks = 0; ks < 2; ++ks)
#pragma unroll
      for (int mi = 0; mi < 4; ++mi)
        aF[ks][mi] = *(const bf16x8*)(Xb + (size_t)(w * 64 + mi * 16 + ll) * DD +
                                      s * 64 + ks * 32 + lg * 8);

    // convert: thread (w,l) produces frag col-block n=w, both ksubs
    const unsigned gb = GBASE + (unsigned)(s & 1) * 32768u;
#pragma unroll
    for (int ks = 0; ks < 2; ++ks) {
      float t0[8];
#pragma unroll
      for (int j = 0; j < 8; ++j)
        t0[j] = *(const float*)(&LDS[gb + (unsigned)(((ks * 32 + lg * 8 + j) * HH) +
                                                     w * 16 + ll) * 4u]);
      ushort8 e;
#pragma unroll
      for (int j = 0; j < 8; ++j) e[j] = f2bf(t0[j]);
      *(ushort8*)(&LDS[FBASE + (unsigned)ks * 8192u + (unsigned)w * 1024u +
                       (unsigned)l * 16u]) = e;
    }

    lds_barrier();     // frag tile visible; all waves done reading G[s&1]

    if (s < 6) G_ISSUE(s + 2);   // refill the buffer just freed

    // 64 MFMAs
#pragma unroll
    for (int ks = 0; ks < 2; ++ks)
#pragma unroll
      for (int n = 0; n < 8; ++n) {
        const bf16x8 b = *(const bf16x8*)(&LDS[FBASE + (unsigned)ks * 8192u +
                                               (unsigned)n * 1024u + (unsigned)l * 16u]);
#pragma unroll
        for (int mi = 0; mi < 4; ++mi)
          acc1[mi][n] = __builtin_amdgcn_mfma_f32_16x16x32_bf16(aF[ks][mi], b, acc1[mi][n], 0, 0, 0);
      }
  }
#undef G_ISSUE

  // barrier2 of step 7 already passed => G region dead for every wave.

  // biases / head weights (fp32, exact)
  float b1v[8], b2v[8], w3v[8];
#pragma unroll
  for (int n = 0; n < 8; ++n) {
    b1v[n] = b1[v * HH + n * 16 + ll];
    b2v[n] = b2[v * HH + n * 16 + ll];
    w3v[n] = W3[v * HH + n * 16 + ll];
  }
  const float b3v = b3[v];

  // W2 -> LDS frag-linear [ki][m]: wave w stages ki=w&3, m=(w>>2)*4+q
  {
    const int ki = w & 3, mb = (w >> 2) * 4;
    float w2t[4][8];
#pragma unroll
    for (int q = 0; q < 4; ++q)
#pragma unroll
      for (int j = 0; j < 8; ++j)
        w2t[q][j] = W2v[(ki * 32 + lg * 8 + j) * HH + (mb + q) * 16 + ll];
#pragma unroll
    for (int q = 0; q < 4; ++q) {
      ushort8 e;
#pragma unroll
      for (int j = 0; j < 8; ++j) e[j] = f2bf(w2t[q][j]);
      *(ushort8*)(&LDS[W2BASE + (unsigned)ki * 8192u + (unsigned)(mb + q) * 1024u +
                       (unsigned)l * 16u]) = e;
    }
  }
  lds_barrier();   // W2L visible to all waves

  const unsigned slot = H1BASE + (unsigned)w * 4096u;  // wave-private 16x128 bf16

  // ---- phase B: layers 2+3, per 16-row block (wave-private h1) ----
#pragma unroll
  for (int mi = 0; mi < 4; ++mi) {
#pragma unroll
    for (int n = 0; n < 8; ++n) {
#pragma unroll
      for (int r = 0; r < 4; ++r) {
        const int tl = lg * 4 + r;
        float hv = acc1[mi][n][r] + b1v[n];
        hv = fmaxf(hv, 0.f);
        const int h = n * 16 + ll;
        const unsigned byte = slot + (unsigned)tl * 256u +
                              (unsigned)((h * 2) ^ ((tl & 7) << 4));
        *(unsigned short*)(&LDS[byte]) = f2bf(hv);
      }
    }
    f32x4 acc2[8];
#pragma unroll
    for (int m = 0; m < 8; ++m) acc2[m] = f32x4{0.f, 0.f, 0.f, 0.f};
#pragma unroll
    for (int ki = 0; ki < 4; ++ki) {
      const int k0 = ki * 32 + lg * 8;
      const unsigned abyte = slot + (unsigned)ll * 256u +
                             (unsigned)((k0 * 2) ^ ((ll & 7) << 4));
      const bf16x8 a2 = *(const bf16x8*)(&LDS[abyte]);
#pragma unroll
      for (int m = 0; m < 8; ++m) {
        const bf16x8 bw = *(const bf16x8*)(&LDS[W2BASE + (unsigned)ki * 8192u +
                                                (unsigned)m * 1024u + (unsigned)l * 16u]);
        acc2[m] = __builtin_amdgcn_mfma_f32_16x16x32_bf16(a2, bw, acc2[m], 0, 0, 0);
      }
    }
#pragma unroll
    for (int r = 0; r < 4; ++r) {
      float p = 0.f;
#pragma unroll
      for (int m = 0; m < 8; ++m)
        p += fmaxf(acc2[m][r] + b2v[m], 0.f) * w3v[m];
      p += __shfl_xor(p, 1);
      p += __shfl_xor(p, 2);
      p += __shfl_xor(p, 4);
      p += __shfl_xor(p, 8);
      if (ll == 0) {
        const int t = w * 64 + mi * 16 + lg * 4 + r;
        out[t * VV + v] = p + b3v;
      }
    }
  }
}

extern "C" void kernel_launch(void* const* d_in, const int* in_sizes, int n_in,
                              void* d_out, int out_size, void* d_ws, size_t ws_size,
                              hipStream_t stream) {
  const float* X  = (const float*)d_in[0];
  const float* W1 = (const float*)d_in[1];
  const float* b1 = (const float*)d_in[2];
  const float* W2 = (const float*)d_in[3];
  const float* b2 = (const float*)d_in[4];
  const float* W3 = (const float*)d_in[5];
  const float* b3 = (const float*)d_in[6];
  float* out = (float*)d_out;

  unsigned short* Xb = (unsigned short*)d_ws;   // 512 KiB bf16 X

  cvt_x_kernel<<<256, 256, 0, stream>>>(X, Xb);
  voxel_mlp_kernel<<<VV, 512, 0, stream>>>(Xb, W1, b1, W2, b2, W3, b3, out);
}